// Round 1
// baseline (744.333 us; speedup 1.0000x reference)
//
#include <hip/hip_runtime.h>

// Problem constants (B=4, H=W=64, C=256, GROUPS=8)
#define N_TOK 4096          // H*W
#define C_DIM 256
#define BATCH 4
#define M_ROWS (BATCH * N_TOK)   // 16384
#define GN_CNT 131072.0f         // 64*64*32 elements per (b, group)

typedef __attribute__((ext_vector_type(4))) float f32x4;
typedef __attribute__((ext_vector_type(8))) short s16x8;      // 8 x bf16 (MFMA A/B frag)
typedef __attribute__((ext_vector_type(4))) unsigned short u16x4;

static __device__ __forceinline__ unsigned short f2bf(float f) {
  unsigned int u = __builtin_bit_cast(unsigned int, f);
  u += 0x7fff + ((u >> 16) & 1);   // RNE
  return (unsigned short)(u >> 16);
}

// ---------------- weight fp32 -> bf16, transposed: wT[n][k] = w[k][n] ----------
__global__ __launch_bounds__(256) void wtrans(const float* __restrict__ wq,
                                              const float* __restrict__ wk,
                                              const float* __restrict__ wv,
                                              const float* __restrict__ wp,
                                              unsigned short* __restrict__ wT) {
  const float* const srcs[4] = {wq, wk, wv, wp};
  const float* w = srcs[blockIdx.z];
  unsigned short* o = wT + blockIdx.z * 65536;
  __shared__ float t[32][33];
  int k0 = blockIdx.x * 32, n0 = blockIdx.y * 32;
  int tx = threadIdx.x, ty = threadIdx.y;
#pragma unroll
  for (int ky = 0; ky < 32; ky += 8)
    t[ty + ky][tx] = w[(k0 + ty + ky) * C_DIM + n0 + tx];
  __syncthreads();
#pragma unroll
  for (int ky = 0; ky < 32; ky += 8)
    o[(n0 + ty + ky) * C_DIM + k0 + tx] = f2bf(t[tx][ty + ky]);
}

// ---------------- GroupNorm partial stats -> atomics into ws ------------------
__global__ __launch_bounds__(256) void gn_stats(const float* __restrict__ x,
                                                float* __restrict__ partials) {
  int bg = blockIdx.x >> 4, chunk = blockIdx.x & 15;
  int b = bg >> 3, g = bg & 7;
  int tid = threadIdx.x;
  const f32x4* x4 = (const f32x4*)x;
  float s1 = 0.f, s2 = 0.f;
#pragma unroll
  for (int it = 0; it < 8; ++it) {
    int idx = it * 256 + tid;          // 0..2047 float4s in this chunk
    int nl = idx >> 3, cq = idx & 7;   // 256 rows x 8 float4s (=32 ch)
    f32x4 v = x4[(b * N_TOK + chunk * 256 + nl) * 64 + g * 8 + cq];
    s1 += v[0] + v[1] + v[2] + v[3];
    s2 += v[0] * v[0] + v[1] * v[1] + v[2] * v[2] + v[3] * v[3];
  }
  for (int m = 1; m < 64; m <<= 1) {
    s1 += __shfl_xor(s1, m, 64);
    s2 += __shfl_xor(s2, m, 64);
  }
  __shared__ float r1[4], r2[4];
  int wave = tid >> 6, lane = tid & 63;
  if (lane == 0) { r1[wave] = s1; r2[wave] = s2; }
  __syncthreads();
  if (tid == 0) {
    atomicAdd(&partials[bg * 2],     r1[0] + r1[1] + r1[2] + r1[3]);
    atomicAdd(&partials[bg * 2 + 1], r2[0] + r2[1] + r2[2] + r2[3]);
  }
}

// ---------------- GroupNorm normalize -> bf16 xn ------------------------------
__global__ __launch_bounds__(256) void gn_norm(const float* __restrict__ x,
                                               const float* __restrict__ gamma,
                                               const float* __restrict__ beta,
                                               const float* __restrict__ partials,
                                               unsigned short* __restrict__ xn) {
  const f32x4* x4 = (const f32x4*)x;
  const f32x4* g4 = (const f32x4*)gamma;
  const f32x4* b4 = (const f32x4*)beta;
  u16x4* o4 = (u16x4*)xn;
  int t0 = blockIdx.x * 256 + threadIdx.x;
#pragma unroll
  for (int it = 0; it < 4; ++it) {
    int fid = it * 262144 + t0;        // over 1,048,576 float4s
    int row = fid >> 6, c4 = fid & 63;
    int b = row >> 12, g = c4 >> 3;
    int bg = b * 8 + g;
    float inv = 1.f / GN_CNT;
    float mean = partials[bg * 2] * inv;
    float var = partials[bg * 2 + 1] * inv - mean * mean;
    float rstd = rsqrtf(var + 1e-3f);
    f32x4 v = x4[fid], ga = g4[c4], be = b4[c4];
    u16x4 o;
#pragma unroll
    for (int j = 0; j < 4; ++j) o[j] = f2bf((v[j] - mean) * rstd * ga[j] + be[j]);
    o4[fid] = o;
  }
}

// ---------------- QKV GEMM: [16384,256] @ 3x[256,256] + bias -> bf16 ----------
// wave = 16 rows; MFMA 16x16x32 bf16; scale (1/16) folded into q.
__global__ __launch_bounds__(256) void qkv_gemm(const unsigned short* __restrict__ xn,
                                                const unsigned short* __restrict__ wT,
                                                const float* __restrict__ bq,
                                                const float* __restrict__ bk,
                                                const float* __restrict__ bv,
                                                unsigned short* __restrict__ qo,
                                                unsigned short* __restrict__ ko,
                                                unsigned short* __restrict__ vo) {
  int tid = threadIdx.x;
  int wave = tid >> 6, lane = tid & 63, g = lane >> 4, c16 = lane & 15;
  int row0 = blockIdx.x * 64 + wave * 16;
  s16x8 af[8];
#pragma unroll
  for (int s = 0; s < 8; ++s)
    af[s] = *(const s16x8*)(xn + (row0 + c16) * C_DIM + s * 32 + g * 8);
  const float* const bs[3] = {bq, bk, bv};
  unsigned short* const outs[3] = {qo, ko, vo};
  const float scl[3] = {0.0625f, 1.f, 1.f};   // q absorbs softmax scale C^-0.5
#pragma unroll
  for (int w = 0; w < 3; ++w) {
    const unsigned short* wt = wT + w * 65536;
    for (int ct = 0; ct < 16; ++ct) {
      float bias = bs[w][ct * 16 + c16];
      f32x4 acc = {bias, bias, bias, bias};
#pragma unroll
      for (int s = 0; s < 8; ++s) {
        s16x8 bf = *(const s16x8*)(wt + (ct * 16 + c16) * C_DIM + s * 32 + g * 8);
        acc = __builtin_amdgcn_mfma_f32_16x16x32_bf16(af[s], bf, acc, 0, 0, 0);
      }
#pragma unroll
      for (int r = 0; r < 4; ++r)
        outs[w][(row0 + g * 4 + r) * C_DIM + ct * 16 + c16] = f2bf(acc[r] * scl[w]);
    }
  }
}

// ---------------- V transpose: v[b][n][c] -> vT[b][c][n] ----------------------
__global__ __launch_bounds__(256) void vtrans(const unsigned short* __restrict__ v,
                                              unsigned short* __restrict__ vT) {
  __shared__ unsigned short t[32][33];
  int n0 = blockIdx.x * 32, c0 = blockIdx.y * 32, b = blockIdx.z;
  int tx = threadIdx.x, ty = threadIdx.y;
#pragma unroll
  for (int ky = 0; ky < 32; ky += 8)
    t[ty + ky][tx] = v[(b * N_TOK + n0 + ty + ky) * C_DIM + c0 + tx];
  __syncthreads();
#pragma unroll
  for (int ky = 0; ky < 32; ky += 8)
    vT[(b * C_DIM + c0 + ty + ky) * N_TOK + n0 + tx] = t[tx][ty + ky];
}

// ---------------- Flash attention: per wave 16 Q rows, j-tiles of 32 ----------
__global__ __launch_bounds__(256) void attn(const unsigned short* __restrict__ q,
                                            const unsigned short* __restrict__ k,
                                            const unsigned short* __restrict__ vT,
                                            unsigned short* __restrict__ o) {
  int tid = threadIdx.x;
  int wave = tid >> 6, lane = tid & 63, g = lane >> 4, c16 = lane & 15;
  int rowbase = blockIdx.x * 64;     // 64 Q rows per block, never spans batches
  int b = rowbase >> 12;
  int qrow0 = rowbase + wave * 16;
  s16x8 qf[8];
#pragma unroll
  for (int s = 0; s < 8; ++s)
    qf[s] = *(const s16x8*)(q + (qrow0 + c16) * C_DIM + s * 32 + g * 8);
  const unsigned short* kb = k + b * N_TOK * C_DIM;
  const unsigned short* vb = vT + b * C_DIM * N_TOK;
  __shared__ __align__(16) unsigned short pb[4][640];  // per-wave 16x(32+8) P tile
  unsigned short* myp = pb[wave];
  f32x4 Oa[16];
#pragma unroll
  for (int ct = 0; ct < 16; ++ct) Oa[ct] = (f32x4){0.f, 0.f, 0.f, 0.f};
  float ms[4] = {-1e30f, -1e30f, -1e30f, -1e30f};
  float ls[4] = {0.f, 0.f, 0.f, 0.f};

  for (int jt = 0; jt < N_TOK / 32; ++jt) {
    int jbase = jt * 32;
    f32x4 s0 = {0.f, 0.f, 0.f, 0.f}, s1 = {0.f, 0.f, 0.f, 0.f};
#pragma unroll
    for (int s = 0; s < 8; ++s) {
      s16x8 k0 = *(const s16x8*)(kb + (jbase + c16) * C_DIM + s * 32 + g * 8);
      s16x8 k1 = *(const s16x8*)(kb + (jbase + 16 + c16) * C_DIM + s * 32 + g * 8);
      s0 = __builtin_amdgcn_mfma_f32_16x16x32_bf16(qf[s], k0, s0, 0, 0, 0);
      s1 = __builtin_amdgcn_mfma_f32_16x16x32_bf16(qf[s], k1, s1, 0, 0, 0);
    }
    // online softmax; S row = g*4+r held by the 16 lanes of group g
    float alpha[4], p0[4], p1[4];
#pragma unroll
    for (int r = 0; r < 4; ++r) {
      float t = fmaxf(s0[r], s1[r]);
      t = fmaxf(t, __shfl_xor(t, 1)); t = fmaxf(t, __shfl_xor(t, 2));
      t = fmaxf(t, __shfl_xor(t, 4)); t = fmaxf(t, __shfl_xor(t, 8));
      float mn = fmaxf(ms[r], t);
      alpha[r] = __expf(ms[r] - mn);
      ms[r] = mn;
      p0[r] = __expf(s0[r] - mn);
      p1[r] = __expf(s1[r] - mn);
      float rs = p0[r] + p1[r];
      rs += __shfl_xor(rs, 1); rs += __shfl_xor(rs, 2);
      rs += __shfl_xor(rs, 4); rs += __shfl_xor(rs, 8);
      ls[r] = ls[r] * alpha[r] + rs;
    }
#pragma unroll
    for (int ct = 0; ct < 16; ++ct)
#pragma unroll
      for (int r = 0; r < 4; ++r) Oa[ct][r] *= alpha[r];
    // P: C-layout -> LDS -> A-layout (per-wave private buffer)
    __syncthreads();
#pragma unroll
    for (int r = 0; r < 4; ++r) {
      myp[(g * 4 + r) * 40 + c16]      = f2bf(p0[r]);
      myp[(g * 4 + r) * 40 + 16 + c16] = f2bf(p1[r]);
    }
    __syncthreads();
    s16x8 pf = *(const s16x8*)(myp + c16 * 40 + g * 8);
#pragma unroll
    for (int ct = 0; ct < 16; ++ct) {
      s16x8 vf = *(const s16x8*)(vb + (ct * 16 + c16) * N_TOK + jbase + g * 8);
      Oa[ct] = __builtin_amdgcn_mfma_f32_16x16x32_bf16(pf, vf, Oa[ct], 0, 0, 0);
    }
  }
  float il[4];
#pragma unroll
  for (int r = 0; r < 4; ++r) il[r] = 1.f / ls[r];
#pragma unroll
  for (int ct = 0; ct < 16; ++ct)
#pragma unroll
    for (int r = 0; r < 4; ++r)
      o[(qrow0 + g * 4 + r) * C_DIM + ct * 16 + c16] = f2bf(Oa[ct][r] * il[r]);
}

// ---------------- Output projection + bias + residual -> fp32 out -------------
__global__ __launch_bounds__(256) void proj_gemm(const unsigned short* __restrict__ a,
                                                 const unsigned short* __restrict__ wt,
                                                 const float* __restrict__ bp,
                                                 const float* __restrict__ x,
                                                 float* __restrict__ out) {
  int tid = threadIdx.x;
  int wave = tid >> 6, lane = tid & 63, g = lane >> 4, c16 = lane & 15;
  int row0 = blockIdx.x * 64 + wave * 16;
  s16x8 af[8];
#pragma unroll
  for (int s = 0; s < 8; ++s)
    af[s] = *(const s16x8*)(a + (row0 + c16) * C_DIM + s * 32 + g * 8);
  for (int ct = 0; ct < 16; ++ct) {
    float bias = bp[ct * 16 + c16];
    f32x4 acc = {bias, bias, bias, bias};
#pragma unroll
    for (int s = 0; s < 8; ++s) {
      s16x8 bf = *(const s16x8*)(wt + (ct * 16 + c16) * C_DIM + s * 32 + g * 8);
      acc = __builtin_amdgcn_mfma_f32_16x16x32_bf16(af[s], bf, acc, 0, 0, 0);
    }
#pragma unroll
    for (int r = 0; r < 4; ++r) {
      int idx = (row0 + g * 4 + r) * C_DIM + ct * 16 + c16;
      out[idx] = acc[r] + x[idx];
    }
  }
}

extern "C" void kernel_launch(void* const* d_in, const int* in_sizes, int n_in,
                              void* d_out, int out_size, void* d_ws, size_t ws_size,
                              hipStream_t stream) {
  const float* x     = (const float*)d_in[0];
  const float* gamma = (const float*)d_in[1];
  const float* beta  = (const float*)d_in[2];
  const float* wq    = (const float*)d_in[3];
  const float* bq    = (const float*)d_in[4];
  const float* wk    = (const float*)d_in[5];
  const float* bk    = (const float*)d_in[6];
  const float* wv    = (const float*)d_in[7];
  const float* bv    = (const float*)d_in[8];
  const float* wp    = (const float*)d_in[9];
  const float* bp    = (const float*)d_in[10];
  float* out = (float*)d_out;

  char* ws = (char*)d_ws;
  float* partials      = (float*)ws;                          // 64 floats
  unsigned short* wT   = (unsigned short*)(ws + 1024);        // 4 x 256x256 bf16
  unsigned short* xnb  = wT + 4 * 65536;                      // xn bf16 [16384,256]
  unsigned short* qb   = xnb + M_ROWS * C_DIM;
  unsigned short* kbuf = qb + M_ROWS * C_DIM;
  unsigned short* vb   = kbuf + M_ROWS * C_DIM;
  unsigned short* vTb  = vb + M_ROWS * C_DIM;
  unsigned short* ab   = xnb;   // reuse xn buffer for attention output (xn dead after qkv)

  hipMemsetAsync(partials, 0, 64 * sizeof(float), stream);
  wtrans<<<dim3(8, 8, 4), dim3(32, 8), 0, stream>>>(wq, wk, wv, wp, wT);
  gn_stats<<<512, 256, 0, stream>>>(x, partials);
  gn_norm<<<1024, 256, 0, stream>>>(x, gamma, beta, partials, xnb);
  qkv_gemm<<<256, 256, 0, stream>>>(xnb, wT, bq, bk, bv, qb, kbuf, vb);
  vtrans<<<dim3(128, 8, 4), dim3(32, 8), 0, stream>>>(vb, vTb);
  attn<<<256, 256, 0, stream>>>(qb, kbuf, vTb, ab);
  proj_gemm<<<256, 256, 0, stream>>>(ab, wT + 3 * 65536, bp, x, out);
}